// Round 7
// baseline (1229.275 us; speedup 1.0000x reference)
//
#include <hip/hip_runtime.h>
#include <stdint.h>

typedef unsigned short u16;
typedef unsigned int u32;
typedef __attribute__((ext_vector_type(8))) short s16x8;
typedef __attribute__((ext_vector_type(4))) float f32x4;

#define P_ 256
#define L_ 64
#define IDIM 512
#define H_ 1024
#define PH (P_ * H_)
#define NG 8            // path-groups
#define GM 32           // rows (paths) per group

__device__ __forceinline__ u16 f2bf(float f){union{float f;u32 u;}v;v.f=f;u32 u=v.u;return (u16)((u+0x7FFFu+((u>>16)&1u))>>16);}
__device__ __forceinline__ float sigf(float x){return 1.0f/(1.0f+__expf(-x));}
__device__ __forceinline__ float tanhf_(float x){return 1.0f-2.0f/(__expf(2.0f*x)+1.0f);}

__device__ __forceinline__ s16x8 pack8v(float4 a, float4 b){
  s16x8 r;
  r[0]=(short)f2bf(a.x); r[1]=(short)f2bf(a.y); r[2]=(short)f2bf(a.z); r[3]=(short)f2bf(a.w);
  r[4]=(short)f2bf(b.x); r[5]=(short)f2bf(b.y); r[6]=(short)f2bf(b.z); r[7]=(short)f2bf(b.w);
  return r;
}
__device__ __forceinline__ s16x8 pack8(const float* s){
  return pack8v(*(const float4*)s, *(const float4*)(s+4));
}
// 16B write-through store (bypasses L2 -> coherent at IF$)
__device__ __forceinline__ void st16_coh(u16* addr, s16x8 v){
  asm volatile("global_store_dwordx4 %0, %1, off sc0 sc1" :: "v"(addr), "v"(v) : "memory");
}
// paired 2-lane bf16 -> one 32-bit write-through store
__device__ __forceinline__ void st_pair(u16* addr, float hv, int lane){
  u32 b = (u32)f2bf(hv);
  u32 other = __shfl_xor(b, 1);
  if ((lane & 1) == 0) {
    u32 w = b | (other << 16);
    __hip_atomic_store((u32*)addr, w, __ATOMIC_RELAXED, __HIP_MEMORY_SCOPE_AGENT);
  }
}
__device__ __forceinline__ void set_flag(u32* f, u32 v){
  __hip_atomic_store(f, v, __ATOMIC_RELAXED, __HIP_MEMORY_SCOPE_AGENT);
}
// wave0: lane l polls flag[l] of own group (coalesced 256B load / iter, no RMW)
__device__ __forceinline__ void poll_flags(u32* fg, u32 target, int wid, int lane){
  if (wid == 0) {
    for (;;) {
      u32 f = __hip_atomic_load(&fg[lane], __ATOMIC_RELAXED, __HIP_MEMORY_SCOPE_AGENT);
      if (__all((int)(f >= target))) break;
      __builtin_amdgcn_s_sleep(1);
    }
  }
  asm volatile("" ::: "memory");
  __syncthreads();
}

// Persistent kernel: 512 blocks = 8 path-groups (32 rows) x 64 unit-blocks (16 units x 4 gates).
// 2 blocks/CU -> two independent recurrence chains share each SIMD (latency hiding).
__global__ void __launch_bounds__(256, 1)
tagger_net(const int* __restrict__ paths, const int* __restrict__ lengths,
           const float* __restrict__ emb,
           const float* __restrict__ Wih, const float* __restrict__ Whh,
           const float* __restrict__ bih, const float* __restrict__ bhh,
           const float* __restrict__ Win, const float* __restrict__ bin,
           const float* __restrict__ Wout, const float* __restrict__ bout,
           const float* __restrict__ Wlin, const float* __restrict__ blin,
           u16* __restrict__ X, u16* __restrict__ Hbuf,
           u16* __restrict__ vbuf, float* __restrict__ pmax,
           u32* flags, float* __restrict__ out)
{
  __shared__ __align__(16) float S[8192];    // 32 KB -> two blocks fit in 160 KB LDS
  const int tid  = threadIdx.x;
  const int wid  = tid >> 6, lane = tid & 63;
  const int lrow = lane & 15, lgrp = lane >> 4;
  const int bid  = blockIdx.x;
  const int g = bid >> 6, jb = bid & 63;
  const int p0 = g * GM, j0 = jb * 16;
  u32* fgrp = flags + g * 64;                // this group's 64 flags (256B line)
  u32* myflag = fgrp + jb;

  // ---- init: gather X[t=jb][p0..p0+31][:] (write-through), zero own Hbuf[0] chunk
  for (int it = 0; it < 8; ++it) {
    int e = (it * 256 + tid) * 8;            // 32 rows x 512 cols
    int row = e >> 9, col = e & 511;
    int tok = paths[(p0 + row) * L_ + jb];
    const float* s = emb + (size_t)tok * IDIM + col;
    float4 a = *(const float4*)s, b4 = *(const float4*)(s + 4);
    st16_coh(X + ((size_t)jb * P_ + p0 + row) * IDIM + col, pack8v(a, b4));
  }
  {
    int row = tid >> 3, cp = tid & 7;        // 256 u32 cells: 32 rows x 8 col-pairs
    __hip_atomic_store((u32*)&Hbuf[(size_t)(p0 + row) * H_ + j0 + cp * 2], 0u,
                       __ATOMIC_RELAXED, __HIP_MEMORY_SCOPE_AGENT);
  }
  __syncthreads();                           // drains vmcnt of all waves
  if (tid == 0) set_flag(myflag, 1u);

  // ---- weights into registers: wave wid owns K chunks c = wid + 4*i (i=0..11) ----
  s16x8 breg[12][4];
#pragma unroll
  for (int i = 0; i < 12; ++i) {
    const int k = (wid + 4 * i) * 32 + lgrp * 8;
#pragma unroll
    for (int fn = 0; fn < 4; ++fn) {
      const int n = fn * H_ + j0 + lrow;
      const float* src = (k < IDIM) ? (Wih + (size_t)n * IDIM + k)
                                    : (Whh + (size_t)n * H_ + (k - IDIM));
      breg[i][fn] = pack8(src);
    }
  }

  // epilogue rows: waves 0,1 own row-halves (waves 2,3 duplicate, stores suppressed)
  const int fmw = wid & 1;
  const int prow = p0 + fmw * 16 + lgrp * 4;
  int lenr[4]; float biasv[4];
#pragma unroll
  for (int r2 = 0; r2 < 4; ++r2) lenr[r2] = lengths[prow + r2];
#pragma unroll
  for (int fn = 0; fn < 4; ++fn) {
    int n = fn * H_ + j0 + lrow;
    biasv[fn] = bih[n] + bhh[n];
  }
  float cst[4] = {0.f,0.f,0.f,0.f}, hst[4] = {0.f,0.f,0.f,0.f};

  poll_flags(fgrp, 1u, wid, lane);           // init done (own group)

  const size_t aX = (size_t)(p0 + lrow) * IDIM + lgrp * 8;
  const size_t aH = (size_t)(p0 + lrow) * H_   + lgrp * 8;

  s16x8 fx[4][2];
#define LOADX(T) do { \
    const u16* Xt_ = X + (size_t)(T) * (P_ * IDIM) + aX; \
    _Pragma("unroll") \
    for (int i_ = 0; i_ < 4; ++i_) { \
      const int k0_ = wid * 32 + i_ * 128; \
      _Pragma("unroll") \
      for (int fm_ = 0; fm_ < 2; ++fm_) \
        fx[i_][fm_] = *(const s16x8*)(Xt_ + (size_t)fm_ * (16 * IDIM) + k0_); \
    } } while (0)

  LOADX(0);

  for (int t = 0; t < L_; ++t) {
    const u16* Hr = Hbuf + (size_t)t * PH;
    u16*       Hw = Hbuf + (size_t)(t + 1) * PH;

    f32x4 acc[2][4];
#pragma unroll
    for (int a = 0; a < 2; ++a)
#pragma unroll
      for (int b = 0; b < 4; ++b)
#pragma unroll
        for (int e = 0; e < 4; ++e) acc[a][b][e] = 0.0f;

    // ---- X phase (independent of other blocks, hides poll) ----
#pragma unroll
    for (int i = 0; i < 4; ++i)
#pragma unroll
      for (int fm = 0; fm < 2; ++fm)
#pragma unroll
        for (int fn = 0; fn < 4; ++fn)
          acc[fm][fn] = __builtin_amdgcn_mfma_f32_16x16x32_bf16(fx[i][fm], breg[i][fn], acc[fm][fn], 0, 0, 0);

    // ---- wait for Hbuf[t] complete (64 sibling blocks) ----
    poll_flags(fgrp, (u32)(t + 1), wid, lane);

    // ---- H phase: plain cached loads (write-once renamed buffers, never stale) ----
    const u16* Hp = Hr + aH;
#pragma unroll
    for (int half = 0; half < 2; ++half) {
      s16x8 fh[4][2];
#pragma unroll
      for (int i = 0; i < 4; ++i) {
        const int kh = wid * 32 + (half * 4 + i) * 128;
#pragma unroll
        for (int fm = 0; fm < 2; ++fm)
          fh[i][fm] = *(const s16x8*)(Hp + (size_t)fm * (16 * H_) + kh);
      }
#pragma unroll
      for (int i = 0; i < 4; ++i)
#pragma unroll
        for (int fm = 0; fm < 2; ++fm)
#pragma unroll
          for (int fn = 0; fn < 4; ++fn)
            acc[fm][fn] = __builtin_amdgcn_mfma_f32_16x16x32_bf16(fh[i][fm], breg[4 + half * 4 + i][fn], acc[fm][fn], 0, 0, 0);
    }

    const int tp1 = (t < L_ - 1) ? (t + 1) : (L_ - 1);
    LOADX(tp1);                              // prefetch next X under epilogue

    // ---- cross-wave K-reduction (32 frags x 256 floats = 32 KB) ----
#pragma unroll
    for (int fm = 0; fm < 2; ++fm)
#pragma unroll
      for (int fn = 0; fn < 4; ++fn)
        *(f32x4*)&S[((wid * 8) + fm * 4 + fn) * 256 + lane * 4] = acc[fm][fn];
    __syncthreads();
    f32x4 red[4];
#pragma unroll
    for (int fn = 0; fn < 4; ++fn) {
      red[fn] = *(const f32x4*)&S[(fmw * 4 + fn) * 256 + lane * 4];
#pragma unroll
      for (int w = 1; w < 4; ++w)
        red[fn] += *(const f32x4*)&S[(w * 8 + fmw * 4 + fn) * 256 + lane * 4];
    }

    // ---- in-register gate epilogue, write-through H (waves 0,1 store) ----
#pragma unroll
    for (int r2 = 0; r2 < 4; ++r2) {
      if (t < lenr[r2]) {
        float gi = red[0][r2] + biasv[0];
        float gf = red[1][r2] + biasv[1];
        float gg = red[2][r2] + biasv[2];
        float go = red[3][r2] + biasv[3];
        float cn = sigf(gf) * cst[r2] + sigf(gi) * tanhf_(gg);
        cst[r2] = cn;
        hst[r2] = sigf(go) * tanhf_(cn);
      }
      if (wid < 2)
        st_pair(&Hw[(size_t)(prow + r2) * H_ + j0 + lrow], hst[r2], lane);
    }
    __syncthreads();                         // drain stores (all waves)
    if (tid == 0) set_flag(myflag, (u32)(t + 2));
  }

  // ================= tail =================
  const u16* hfin = Hbuf + (size_t)L_ * PH;
  poll_flags(fgrp, 65u, wid, lane);

  // ---- v = h@Wv^T + bv ----
  {
    f32x4 acc2[2];
#pragma unroll
    for (int a = 0; a < 2; ++a)
#pragma unroll
      for (int e = 0; e < 4; ++e) acc2[a][e] = 0.0f;
    const u16* hp = hfin + aH;
    const float* wv = Win + (size_t)(2 * H_ + j0 + lrow) * H_;
#pragma unroll
    for (int ic = 0; ic < 8; ++ic) {
      const int k0 = wid * 256 + ic * 32;
      s16x8 fbv = pack8(wv + k0 + lgrp * 8);
#pragma unroll
      for (int fm = 0; fm < 2; ++fm) {
        s16x8 fav = *(const s16x8*)(hp + (size_t)fm * (16 * H_) + k0);
        acc2[fm] = __builtin_amdgcn_mfma_f32_16x16x32_bf16(fav, fbv, acc2[fm], 0, 0, 0);
      }
    }
#pragma unroll
    for (int fm = 0; fm < 2; ++fm)
      *(f32x4*)&S[(wid * 2 + fm) * 256 + lane * 4] = acc2[fm];
    __syncthreads();
    f32x4 rv = *(const f32x4*)&S[(fmw) * 256 + lane * 4];
#pragma unroll
    for (int w = 1; w < 4; ++w)
      rv += *(const f32x4*)&S[(w * 2 + fmw) * 256 + lane * 4];
    float bvj = bin[2 * H_ + j0 + lrow];
    if (wid < 2)
#pragma unroll
      for (int r2 = 0; r2 < 4; ++r2)
        st_pair(&vbuf[(size_t)(prow + r2) * H_ + j0 + lrow], rv[r2] + bvj, lane);
  }
  __syncthreads();
  if (tid == 0) set_flag(myflag, 66u);
  poll_flags(fgrp, 66u, wid, lane);

  // ---- attn = v@Wout^T + bout, then per-block max over own 32 rows ----
  {
    f32x4 acc2[2];
#pragma unroll
    for (int a = 0; a < 2; ++a)
#pragma unroll
      for (int e = 0; e < 4; ++e) acc2[a][e] = 0.0f;
    const u16* vp = vbuf + aH;
    const float* wo = Wout + (size_t)(j0 + lrow) * H_;
#pragma unroll
    for (int ic = 0; ic < 8; ++ic) {
      const int k0 = wid * 256 + ic * 32;
      s16x8 fbv = pack8(wo + k0 + lgrp * 8);
#pragma unroll
      for (int fm = 0; fm < 2; ++fm) {
        s16x8 fav = *(const s16x8*)(vp + (size_t)fm * (16 * H_) + k0);
        acc2[fm] = __builtin_amdgcn_mfma_f32_16x16x32_bf16(fav, fbv, acc2[fm], 0, 0, 0);
      }
    }
#pragma unroll
    for (int fm = 0; fm < 2; ++fm)
      *(f32x4*)&S[(wid * 2 + fm) * 256 + lane * 4] = acc2[fm];
    __syncthreads();
    f32x4 rv = *(const f32x4*)&S[(fmw) * 256 + lane * 4];
#pragma unroll
    for (int w = 1; w < 4; ++w)
      rv += *(const f32x4*)&S[(w * 2 + fmw) * 256 + lane * 4];
    float bo = bout[j0 + lrow];
    float m = fmaxf(fmaxf(rv[0], rv[1]), fmaxf(rv[2], rv[3])) + bo;
    __syncthreads();
    S[(wid * 4 + lgrp) * 16 + lrow] = m;     // waves 2,3 write duplicates (max-safe)
    __syncthreads();
    if (tid < 16) {
      float mx = S[tid];
#pragma unroll
      for (int s2 = 1; s2 < 16; ++s2) mx = fmaxf(mx, S[s2 * 16 + tid]);
      __hip_atomic_store(&pmax[(size_t)g * H_ + j0 + tid], mx, __ATOMIC_RELAXED, __HIP_MEMORY_SCOPE_AGENT);
    }
  }
  __syncthreads();
  if (tid == 0) set_flag(myflag, 67u);

  if (bid != 0) return;

  // ---- final: max over 8 groups, 1024->2 dot, sigmoid ----
  if (wid == 0) {
    for (int g2 = 0; g2 < NG; ++g2) {
      for (;;) {
        u32 f = __hip_atomic_load(&flags[g2 * 64 + lane], __ATOMIC_RELAXED, __HIP_MEMORY_SCOPE_AGENT);
        if (__all((int)(f >= 67u))) break;
        __builtin_amdgcn_s_sleep(1);
      }
    }
  }
  asm volatile("" ::: "memory");
  __syncthreads();
  {
    int j4 = tid * 4;
    float s0 = 0.f, s1 = 0.f;
#pragma unroll
    for (int e = 0; e < 4; ++e) {
      float pv = pmax[j4 + e];
#pragma unroll
      for (int gg2 = 1; gg2 < NG; ++gg2) pv = fmaxf(pv, pmax[gg2 * H_ + j4 + e]);
      s0 += pv * Wlin[j4 + e];
      s1 += pv * Wlin[H_ + j4 + e];
    }
    S[tid] = s0; S[256 + tid] = s1;
    __syncthreads();
    for (int s2 = 128; s2 > 0; s2 >>= 1) {
      if (tid < s2) { S[tid] += S[tid + s2]; S[256 + tid] += S[256 + tid + s2]; }
      __syncthreads();
    }
    if (tid == 0) {
      out[0] = sigf(S[0] + blin[0]);
      out[1] = sigf(S[256] + blin[1]);
    }
  }
}

extern "C" void kernel_launch(void* const* d_in, const int* in_sizes, int n_in,
                              void* d_out, int out_size, void* d_ws, size_t ws_size,
                              hipStream_t stream) {
  const int*   paths   = (const int*)d_in[0];
  const int*   lengths = (const int*)d_in[1];
  const float* emb     = (const float*)d_in[2];
  const float* Wih     = (const float*)d_in[3];
  const float* Whh     = (const float*)d_in[4];
  const float* bih     = (const float*)d_in[5];
  const float* bhh     = (const float*)d_in[6];
  const float* Win     = (const float*)d_in[7];
  const float* bin     = (const float*)d_in[8];
  const float* Wout    = (const float*)d_in[9];
  const float* bout    = (const float*)d_in[10];
  const float* Wlin    = (const float*)d_in[11];
  const float* blin    = (const float*)d_in[12];
  float* out = (float*)d_out;

  char* ws = (char*)d_ws;
  u32*   flags  = (u32*)  (ws);                  //      2,048 (8 groups x 64 flags)
  float* pmax   = (float*)(ws + 4096);           //     32,768 (8 groups x 1024)
  u16*   X      = (u16*)  (ws + 65536);          // 16,777,216
  u16*   Hbuf   = (u16*)  (ws + 16842752);       // 65 x 524,288 = 34,078,720
  u16*   vbuf   = (u16*)  (ws + 50921472);       //    524,288   (total ~51.4 MB)

  hipMemsetAsync(flags, 0, 2048, stream);
  tagger_net<<<512, 256, 0, stream>>>(paths, lengths, emb, Wih, Whh, bih, bhh,
                                      Win, bin, Wout, bout, Wlin, blin,
                                      X, Hbuf, vbuf, pmax, flags, out);
}

// Round 8
// 820.136 us; speedup vs baseline: 1.4989x; 1.4989x over previous
//
#include <hip/hip_runtime.h>
#include <stdint.h>

typedef unsigned short u16;
typedef unsigned int u32;
typedef __attribute__((ext_vector_type(8))) short s16x8;
typedef __attribute__((ext_vector_type(4))) float f32x4;

#define P_ 256
#define L_ 64
#define IDIM 512
#define H_ 1024
#define PH (P_ * H_)

__device__ __forceinline__ u16 f2bf(float f){union{float f;u32 u;}v;v.f=f;u32 u=v.u;return (u16)((u+0x7FFFu+((u>>16)&1u))>>16);}
__device__ __forceinline__ float sigf(float x){return 1.0f/(1.0f+__expf(-x));}
__device__ __forceinline__ float tanhf_(float x){return 1.0f-2.0f/(__expf(2.0f*x)+1.0f);}

__device__ __forceinline__ s16x8 pack8v(float4 a, float4 b){
  s16x8 r;
  r[0]=(short)f2bf(a.x); r[1]=(short)f2bf(a.y); r[2]=(short)f2bf(a.z); r[3]=(short)f2bf(a.w);
  r[4]=(short)f2bf(b.x); r[5]=(short)f2bf(b.y); r[6]=(short)f2bf(b.z); r[7]=(short)f2bf(b.w);
  return r;
}
__device__ __forceinline__ s16x8 pack8(const float* s){
  return pack8v(*(const float4*)s, *(const float4*)(s+4));
}
// 16B write-through store (bypasses L2 -> coherent at IF$)
__device__ __forceinline__ void st16_coh(u16* addr, s16x8 v){
  asm volatile("global_store_dwordx4 %0, %1, off sc0 sc1" :: "v"(addr), "v"(v) : "memory");
}
// paired 2-lane bf16 -> one 32-bit write-through store
__device__ __forceinline__ void st_pair(u16* addr, float hv, int lane){
  u32 b = (u32)f2bf(hv);
  u32 other = __shfl_xor(b, 1);
  if ((lane & 1) == 0) {
    u32 w = b | (other << 16);
    __hip_atomic_store((u32*)addr, w, __ATOMIC_RELAXED, __HIP_MEMORY_SCOPE_AGENT);
  }
}
__device__ __forceinline__ void set_flag(u32* f, u32 v){
  __hip_atomic_store(f, v, __ATOMIC_RELAXED, __HIP_MEMORY_SCOPE_AGENT);
}
// wave0: lane l polls flag[l] of own group (coalesced 256B load / iter, no RMW)
__device__ __forceinline__ void poll_flags(u32* fg, u32 target, int wid, int lane){
  if (wid == 0) {
    for (;;) {
      u32 f = __hip_atomic_load(&fg[lane], __ATOMIC_RELAXED, __HIP_MEMORY_SCOPE_AGENT);
      if (__all((int)(f >= target))) break;
      __builtin_amdgcn_s_sleep(1);
    }
  }
  asm volatile("" ::: "memory");
  __syncthreads();
}

// Persistent kernel: 256 blocks = 4 path-groups x 64 unit-blocks (16 units x 4 gates).
// H renamed per step (Hbuf[t]). Publish tail restructured: stores -> X-MFMA(t+1) ->
// LOADX(t+2) -> counted vmcnt(16) (acks stores, keeps X loads flying) -> raw barrier -> flag.
__global__ void __launch_bounds__(256, 1)
tagger_net(const int* __restrict__ paths, const int* __restrict__ lengths,
           const float* __restrict__ emb,
           const float* __restrict__ Wih, const float* __restrict__ Whh,
           const float* __restrict__ bih, const float* __restrict__ bhh,
           const float* __restrict__ Win, const float* __restrict__ bin,
           const float* __restrict__ Wout, const float* __restrict__ bout,
           const float* __restrict__ Wlin, const float* __restrict__ blin,
           u16* __restrict__ X, u16* __restrict__ Hbuf,
           u16* __restrict__ vbuf, float* __restrict__ pmax,
           u32* flags, float* __restrict__ out)
{
  __shared__ __align__(16) float S[16384];   // 64 KB K-reduction scratch
  const int tid  = threadIdx.x;
  const int wid  = tid >> 6, lane = tid & 63;
  const int lrow = lane & 15, lgrp = lane >> 4;
  const int bid  = blockIdx.x;
  const int g = bid >> 6, jb = bid & 63;
  const int p0 = g * 64, j0 = jb * 16;
  u32* fgrp = flags + g * 64;
  u32* myflag = fgrp + jb;

  // ---- init: gather X[t=jb][p0..p0+63][:] (write-through), zero own Hbuf[0] chunk
  for (int it = 0; it < 16; ++it) {
    int e = (it * 256 + tid) * 8;
    int row = e >> 9, col = e & 511;
    int tok = paths[(p0 + row) * L_ + jb];
    const float* s = emb + (size_t)tok * IDIM + col;
    float4 a = *(const float4*)s, b4 = *(const float4*)(s + 4);
    st16_coh(X + ((size_t)jb * P_ + p0 + row) * IDIM + col, pack8v(a, b4));
  }
#pragma unroll
  for (int i = 0; i < 2; ++i) {
    int idx = tid * 2 + i;
    int row = idx >> 3, cp = idx & 7;
    __hip_atomic_store((u32*)&Hbuf[(size_t)(p0 + row) * H_ + j0 + cp * 2], 0u,
                       __ATOMIC_RELAXED, __HIP_MEMORY_SCOPE_AGENT);
  }
  __syncthreads();                            // drains vmcnt of all waves
  if (tid == 0) set_flag(myflag, 1u);

  // ---- weights into registers: wave wid owns K chunks c = wid + 4*i ----
  s16x8 breg[12][4];
#pragma unroll
  for (int i = 0; i < 12; ++i) {
    const int k = (wid + 4 * i) * 32 + lgrp * 8;
#pragma unroll
    for (int fn = 0; fn < 4; ++fn) {
      const int n = fn * H_ + j0 + lrow;
      const float* src = (k < IDIM) ? (Wih + (size_t)n * IDIM + k)
                                    : (Whh + (size_t)n * H_ + (k - IDIM));
      breg[i][fn] = pack8(src);
    }
  }

  const int prow = p0 + wid * 16 + lgrp * 4;
  int lenr[4]; float biasv[4];
#pragma unroll
  for (int r2 = 0; r2 < 4; ++r2) lenr[r2] = lengths[prow + r2];
#pragma unroll
  for (int fn = 0; fn < 4; ++fn) {
    int n = fn * H_ + j0 + lrow;
    biasv[fn] = bih[n] + bhh[n];
  }
  float cst[4] = {0.f,0.f,0.f,0.f}, hst[4] = {0.f,0.f,0.f,0.f};

  const size_t aX = (size_t)(p0 + lrow) * IDIM + lgrp * 8;
  const size_t aH = (size_t)(p0 + lrow) * H_   + lgrp * 8;

  s16x8 fx[4][4];
#define LOADX(T) do { \
    const u16* Xt_ = X + (size_t)(T) * (P_ * IDIM) + aX; \
    _Pragma("unroll") \
    for (int i_ = 0; i_ < 4; ++i_) { \
      const int k0_ = wid * 32 + i_ * 128; \
      _Pragma("unroll") \
      for (int fm_ = 0; fm_ < 4; ++fm_) \
        fx[i_][fm_] = *(const s16x8*)(Xt_ + (size_t)fm_ * (16 * IDIM) + k0_); \
    } } while (0)

  f32x4 acc[4][4];

  // prologue: X(0) contribution into acc; prefetch X(1) for first publish-tail
  poll_flags(fgrp, 1u, wid, lane);            // X fully gathered (own group) + H0 init
  LOADX(0);
#pragma unroll
  for (int a = 0; a < 4; ++a)
#pragma unroll
    for (int b = 0; b < 4; ++b)
#pragma unroll
      for (int e = 0; e < 4; ++e) acc[a][b][e] = 0.0f;
#pragma unroll
  for (int i = 0; i < 4; ++i)
#pragma unroll
    for (int fm = 0; fm < 4; ++fm)
#pragma unroll
      for (int fn = 0; fn < 4; ++fn)
        acc[fm][fn] = __builtin_amdgcn_mfma_f32_16x16x32_bf16(fx[i][fm], breg[i][fn], acc[fm][fn], 0, 0, 0);
  LOADX(1);

  for (int t = 0; t < L_; ++t) {
    const u16* Hr = Hbuf + (size_t)t * PH;
    u16*       Hw = Hbuf + (size_t)(t + 1) * PH;

    // ---- A: wait for Hbuf[t] (64 sibling blocks) ----
    poll_flags(fgrp, (u32)(t + 1), wid, lane);

    // ---- B: H phase, plain cached loads (renamed buffer, never stale) ----
    const u16* Hp = Hr + aH;
#pragma unroll
    for (int half = 0; half < 2; ++half) {
      s16x8 fh[4][4];
#pragma unroll
      for (int i = 0; i < 4; ++i) {
        const int kh = wid * 32 + (half * 4 + i) * 128;
#pragma unroll
        for (int fm = 0; fm < 4; ++fm)
          fh[i][fm] = *(const s16x8*)(Hp + (size_t)fm * (16 * H_) + kh);
      }
#pragma unroll
      for (int i = 0; i < 4; ++i)
#pragma unroll
        for (int fm = 0; fm < 4; ++fm)
#pragma unroll
          for (int fn = 0; fn < 4; ++fn)
            acc[fm][fn] = __builtin_amdgcn_mfma_f32_16x16x32_bf16(fh[i][fm], breg[4 + half * 4 + i][fn], acc[fm][fn], 0, 0, 0);
    }

    // ---- C: cross-wave K-reduction ----
#pragma unroll
    for (int fm = 0; fm < 4; ++fm)
#pragma unroll
      for (int fn = 0; fn < 4; ++fn)
        *(f32x4*)&S[((wid * 16) + fm * 4 + fn) * 256 + lane * 4] = acc[fm][fn];
    __syncthreads();
    f32x4 red[4];
#pragma unroll
    for (int fn = 0; fn < 4; ++fn) {
      red[fn] = *(const f32x4*)&S[(wid * 4 + fn) * 256 + lane * 4];
#pragma unroll
      for (int w = 1; w < 4; ++w)
        red[fn] += *(const f32x4*)&S[(w * 16 + wid * 4 + fn) * 256 + lane * 4];
    }

    // ---- D: in-register gate epilogue ----
#pragma unroll
    for (int r2 = 0; r2 < 4; ++r2) {
      if (t < lenr[r2]) {
        float gi = red[0][r2] + biasv[0];
        float gf = red[1][r2] + biasv[1];
        float gg = red[2][r2] + biasv[2];
        float go = red[3][r2] + biasv[3];
        float cn = sigf(gf) * cst[r2] + sigf(gi) * tanhf_(gg);
        cst[r2] = cn;
        hst[r2] = sigf(go) * tanhf_(cn);
      }
    }
    // ---- E: publish h(t+1): 4 write-through u32 stores per wave ----
#pragma unroll
    for (int r2 = 0; r2 < 4; ++r2)
      st_pair(&Hw[(size_t)(prow + r2) * H_ + j0 + lrow], hst[r2], lane);

    // ---- F: X-MFMA(t+1) into fresh acc (hides store ack) ----
#pragma unroll
    for (int a = 0; a < 4; ++a)
#pragma unroll
      for (int b = 0; b < 4; ++b)
#pragma unroll
        for (int e = 0; e < 4; ++e) acc[a][b][e] = 0.0f;
#pragma unroll
    for (int i = 0; i < 4; ++i)
#pragma unroll
      for (int fm = 0; fm < 4; ++fm)
#pragma unroll
        for (int fn = 0; fn < 4; ++fn)
          acc[fm][fn] = __builtin_amdgcn_mfma_f32_16x16x32_bf16(fx[i][fm], breg[i][fn], acc[fm][fn], 0, 0, 0);

    // ---- G: prefetch X(t+2) (16 loads; stay in flight across the barrier) ----
    { const int tp2 = (t + 2 <= L_ - 1) ? (t + 2) : (L_ - 1); LOADX(tp2); }

    // ---- H: counted drain (acks the 4 older stores; X loads keep flying),
    //         raw barrier (no full vmcnt0 drain), then flag ----
    asm volatile("s_waitcnt vmcnt(16)" ::: "memory");
    __builtin_amdgcn_s_barrier();
    if (tid == 0) set_flag(myflag, (u32)(t + 2));
  }

  // ================= tail =================
  const u16* hfin = Hbuf + (size_t)L_ * PH;
  poll_flags(fgrp, 65u, wid, lane);

  // ---- v = h@Wv^T + bv ----
  {
    f32x4 acc2[4];
#pragma unroll
    for (int a = 0; a < 4; ++a)
#pragma unroll
      for (int e = 0; e < 4; ++e) acc2[a][e] = 0.0f;
    const u16* hp = hfin + aH;
    const float* wv = Win + (size_t)(2 * H_ + j0 + lrow) * H_;
#pragma unroll
    for (int ic = 0; ic < 8; ++ic) {
      const int k0 = wid * 256 + ic * 32;
      s16x8 fbv = pack8(wv + k0 + lgrp * 8);
#pragma unroll
      for (int fm = 0; fm < 4; ++fm) {
        s16x8 fav = *(const s16x8*)(hp + (size_t)fm * (16 * H_) + k0);
        acc2[fm] = __builtin_amdgcn_mfma_f32_16x16x32_bf16(fav, fbv, acc2[fm], 0, 0, 0);
      }
    }
#pragma unroll
    for (int fm = 0; fm < 4; ++fm)
      *(f32x4*)&S[(wid * 4 + fm) * 256 + lane * 4] = acc2[fm];
    __syncthreads();
    f32x4 rv = *(const f32x4*)&S[(wid) * 256 + lane * 4];
#pragma unroll
    for (int w = 1; w < 4; ++w)
      rv += *(const f32x4*)&S[(w * 4 + wid) * 256 + lane * 4];
    float bvj = bin[2 * H_ + j0 + lrow];
#pragma unroll
    for (int r2 = 0; r2 < 4; ++r2)
      st_pair(&vbuf[(size_t)(prow + r2) * H_ + j0 + lrow], rv[r2] + bvj, lane);
  }
  __syncthreads();
  if (tid == 0) set_flag(myflag, 66u);
  poll_flags(fgrp, 66u, wid, lane);

  // ---- attn = v@Wout^T + bout, then per-block max over own 64 rows ----
  {
    f32x4 acc2[4];
#pragma unroll
    for (int a = 0; a < 4; ++a)
#pragma unroll
      for (int e = 0; e < 4; ++e) acc2[a][e] = 0.0f;
    const u16* vp = vbuf + aH;
    const float* wo = Wout + (size_t)(j0 + lrow) * H_;
#pragma unroll
    for (int ic = 0; ic < 8; ++ic) {
      const int k0 = wid * 256 + ic * 32;
      s16x8 fbv = pack8(wo + k0 + lgrp * 8);
#pragma unroll
      for (int fm = 0; fm < 4; ++fm) {
        s16x8 fav = *(const s16x8*)(vp + (size_t)fm * (16 * H_) + k0);
        acc2[fm] = __builtin_amdgcn_mfma_f32_16x16x32_bf16(fav, fbv, acc2[fm], 0, 0, 0);
      }
    }
#pragma unroll
    for (int fm = 0; fm < 4; ++fm)
      *(f32x4*)&S[(wid * 4 + fm) * 256 + lane * 4] = acc2[fm];
    __syncthreads();
    f32x4 rv = *(const f32x4*)&S[(wid) * 256 + lane * 4];
#pragma unroll
    for (int w = 1; w < 4; ++w)
      rv += *(const f32x4*)&S[(w * 4 + wid) * 256 + lane * 4];
    float bo = bout[j0 + lrow];
    float m = fmaxf(fmaxf(rv[0], rv[1]), fmaxf(rv[2], rv[3])) + bo;
    __syncthreads();
    S[(wid * 4 + lgrp) * 16 + lrow] = m;
    __syncthreads();
    if (tid < 16) {
      float mx = S[tid];
#pragma unroll
      for (int s2 = 1; s2 < 16; ++s2) mx = fmaxf(mx, S[s2 * 16 + tid]);
      __hip_atomic_store(&pmax[(size_t)g * H_ + j0 + tid], mx, __ATOMIC_RELAXED, __HIP_MEMORY_SCOPE_AGENT);
    }
  }
  __syncthreads();
  if (tid == 0) set_flag(myflag, 67u);

  if (bid != 0) return;

  // ---- final: max over groups, 1024->2 dot, sigmoid ----
  if (wid == 0) {
    for (int g2 = 0; g2 < 4; ++g2) {
      for (;;) {
        u32 f = __hip_atomic_load(&flags[g2 * 64 + lane], __ATOMIC_RELAXED, __HIP_MEMORY_SCOPE_AGENT);
        if (__all((int)(f >= 67u))) break;
        __builtin_amdgcn_s_sleep(1);
      }
    }
  }
  asm volatile("" ::: "memory");
  __syncthreads();
  {
    int j4 = tid * 4;
    float s0 = 0.f, s1 = 0.f;
#pragma unroll
    for (int e = 0; e < 4; ++e) {
      float pv = pmax[j4 + e];
#pragma unroll
      for (int gg2 = 1; gg2 < 4; ++gg2) pv = fmaxf(pv, pmax[gg2 * H_ + j4 + e]);
      s0 += pv * Wlin[j4 + e];
      s1 += pv * Wlin[H_ + j4 + e];
    }
    S[tid] = s0; S[256 + tid] = s1;
    __syncthreads();
    for (int s2 = 128; s2 > 0; s2 >>= 1) {
      if (tid < s2) { S[tid] += S[tid + s2]; S[256 + tid] += S[256 + tid + s2]; }
      __syncthreads();
    }
    if (tid == 0) {
      out[0] = sigf(S[0] + blin[0]);
      out[1] = sigf(S[256] + blin[1]);
    }
  }
}

extern "C" void kernel_launch(void* const* d_in, const int* in_sizes, int n_in,
                              void* d_out, int out_size, void* d_ws, size_t ws_size,
                              hipStream_t stream) {
  const int*   paths   = (const int*)d_in[0];
  const int*   lengths = (const int*)d_in[1];
  const float* emb     = (const float*)d_in[2];
  const float* Wih     = (const float*)d_in[3];
  const float* Whh     = (const float*)d_in[4];
  const float* bih     = (const float*)d_in[5];
  const float* bhh     = (const float*)d_in[6];
  const float* Win     = (const float*)d_in[7];
  const float* bin     = (const float*)d_in[8];
  const float* Wout    = (const float*)d_in[9];
  const float* bout    = (const float*)d_in[10];
  const float* Wlin    = (const float*)d_in[11];
  const float* blin    = (const float*)d_in[12];
  float* out = (float*)d_out;

  char* ws = (char*)d_ws;
  u32*   flags  = (u32*)  (ws);                  //      1,024 (256 u32; group g at +g*256B)
  float* pmax   = (float*)(ws + 4096);           //     16,384
  u16*   X      = (u16*)  (ws + 32768);          // 16,777,216
  u16*   Hbuf   = (u16*)  (ws + 16810240);       // 65 x 524,288 = 34,078,720
  u16*   vbuf   = (u16*)  (ws + 50888960);       //    524,288   (total ~51.4 MB)

  hipMemsetAsync(flags, 0, 1024, stream);
  tagger_net<<<256, 256, 0, stream>>>(paths, lengths, emb, Wih, Whh, bih, bhh,
                                      Win, bin, Wout, bout, Wlin, blin,
                                      X, Hbuf, vbuf, pmax, flags, out);
}

// Round 9
// 606.184 us; speedup vs baseline: 2.0279x; 1.3529x over previous
//
#include <hip/hip_runtime.h>
#include <stdint.h>

typedef unsigned short u16;
typedef unsigned int u32;
typedef __attribute__((ext_vector_type(8))) short s16x8;
typedef __attribute__((ext_vector_type(4))) float f32x4;

#define P_ 256
#define L_ 64
#define IDIM 512
#define H_ 1024
#define PH (P_ * H_)

__device__ __forceinline__ u16 f2bf(float f){union{float f;u32 u;}v;v.f=f;u32 u=v.u;return (u16)((u+0x7FFFu+((u>>16)&1u))>>16);}
__device__ __forceinline__ float sigf(float x){return 1.0f/(1.0f+__expf(-x));}
__device__ __forceinline__ float tanhf_(float x){return 1.0f-2.0f/(__expf(2.0f*x)+1.0f);}

__device__ __forceinline__ s16x8 pack8v(float4 a, float4 b){
  s16x8 r;
  r[0]=(short)f2bf(a.x); r[1]=(short)f2bf(a.y); r[2]=(short)f2bf(a.z); r[3]=(short)f2bf(a.w);
  r[4]=(short)f2bf(b.x); r[5]=(short)f2bf(b.y); r[6]=(short)f2bf(b.z); r[7]=(short)f2bf(b.w);
  return r;
}
__device__ __forceinline__ s16x8 pack8(const float* s){
  return pack8v(*(const float4*)s, *(const float4*)(s+4));
}
// 16B write-through store (bypasses L2 -> coherent at IF$)
__device__ __forceinline__ void st16_coh(u16* addr, s16x8 v){
  asm volatile("global_store_dwordx4 %0, %1, off sc0 sc1" :: "v"(addr), "v"(v) : "memory");
}
// paired 2-lane bf16 -> one 32-bit write-through store
__device__ __forceinline__ void st_pair(u16* addr, float hv, int lane){
  u32 b = (u32)f2bf(hv);
  u32 other = __shfl_xor(b, 1);
  if ((lane & 1) == 0) {
    u32 w = b | (other << 16);
    __hip_atomic_store((u32*)addr, w, __ATOMIC_RELAXED, __HIP_MEMORY_SCOPE_AGENT);
  }
}
__device__ __forceinline__ void set_flag(u32* f, u32 v){
  __hip_atomic_store(f, v, __ATOMIC_RELAXED, __HIP_MEMORY_SCOPE_AGENT);
}
// wave0: lane l polls flag[l] of own group (coalesced 256B load / iter, no RMW)
__device__ __forceinline__ void poll_flags(u32* fg, u32 target, int wid, int lane){
  if (wid == 0) {
    for (;;) {
      u32 f = __hip_atomic_load(&fg[lane], __ATOMIC_RELAXED, __HIP_MEMORY_SCOPE_AGENT);
      if (__all((int)(f >= target))) break;
      __builtin_amdgcn_s_sleep(1);
    }
  }
  asm volatile("" ::: "memory");
  __syncthreads();
}

// Persistent kernel: 256 blocks = 4 path-groups x 64 unit-blocks (16 units x 4 gates).
// XCD-clustered mapping: g = bid&3 -> each group's 64 blocks land on 2 XCDs
// (round-robin dispatch, XCD ~ bid%8) so the per-step H tile is L2-shared by
// 32 consumers per XCD instead of fetched from IF$ by all 8 XCDs.
__global__ void __launch_bounds__(256, 1)
tagger_net(const int* __restrict__ paths, const int* __restrict__ lengths,
           const float* __restrict__ emb,
           const float* __restrict__ Wih, const float* __restrict__ Whh,
           const float* __restrict__ bih, const float* __restrict__ bhh,
           const float* __restrict__ Win, const float* __restrict__ bin,
           const float* __restrict__ Wout, const float* __restrict__ bout,
           const float* __restrict__ Wlin, const float* __restrict__ blin,
           u16* __restrict__ X, u16* __restrict__ Hbuf,
           u16* __restrict__ vbuf, float* __restrict__ pmax,
           u32* flags, float* __restrict__ out)
{
  __shared__ __align__(16) float S[16384];   // 64 KB K-reduction scratch
  const int tid  = threadIdx.x;
  const int wid  = tid >> 6, lane = tid & 63;
  const int lrow = lane & 15, lgrp = lane >> 4;
  const int bid  = blockIdx.x;
  const int g = bid & 3, jb = bid >> 2;      // XCD-clustered group mapping
  const int p0 = g * 64, j0 = jb * 16;
  u32* fgrp = flags + g * 64;
  u32* myflag = fgrp + jb;

  // ---- init: gather X[t=jb][p0..p0+63][:] (write-through), zero own Hbuf[0] chunk
  for (int it = 0; it < 16; ++it) {
    int e = (it * 256 + tid) * 8;
    int row = e >> 9, col = e & 511;
    int tok = paths[(p0 + row) * L_ + jb];
    const float* s = emb + (size_t)tok * IDIM + col;
    float4 a = *(const float4*)s, b4 = *(const float4*)(s + 4);
    st16_coh(X + ((size_t)jb * P_ + p0 + row) * IDIM + col, pack8v(a, b4));
  }
#pragma unroll
  for (int i = 0; i < 2; ++i) {
    int idx = tid * 2 + i;
    int row = idx >> 3, cp = idx & 7;
    __hip_atomic_store((u32*)&Hbuf[(size_t)(p0 + row) * H_ + j0 + cp * 2], 0u,
                       __ATOMIC_RELAXED, __HIP_MEMORY_SCOPE_AGENT);
  }
  __syncthreads();                            // drains vmcnt of all waves
  if (tid == 0) set_flag(myflag, 1u);

  // ---- weights into registers: wave wid owns K chunks c = wid + 4*i ----
  s16x8 breg[12][4];
#pragma unroll
  for (int i = 0; i < 12; ++i) {
    const int k = (wid + 4 * i) * 32 + lgrp * 8;
#pragma unroll
    for (int fn = 0; fn < 4; ++fn) {
      const int n = fn * H_ + j0 + lrow;
      const float* src = (k < IDIM) ? (Wih + (size_t)n * IDIM + k)
                                    : (Whh + (size_t)n * H_ + (k - IDIM));
      breg[i][fn] = pack8(src);
    }
  }

  const int prow = p0 + wid * 16 + lgrp * 4;
  int lenr[4]; float biasv[4];
#pragma unroll
  for (int r2 = 0; r2 < 4; ++r2) lenr[r2] = lengths[prow + r2];
#pragma unroll
  for (int fn = 0; fn < 4; ++fn) {
    int n = fn * H_ + j0 + lrow;
    biasv[fn] = bih[n] + bhh[n];
  }
  float cst[4] = {0.f,0.f,0.f,0.f}, hst[4] = {0.f,0.f,0.f,0.f};

  poll_flags(fgrp, 1u, wid, lane);            // init done (own group)

  const size_t aX = (size_t)(p0 + lrow) * IDIM + lgrp * 8;
  const size_t aH = (size_t)(p0 + lrow) * H_   + lgrp * 8;

  s16x8 fx[4][4];
#define LOADX(T) do { \
    const u16* Xt_ = X + (size_t)(T) * (P_ * IDIM) + aX; \
    _Pragma("unroll") \
    for (int i_ = 0; i_ < 4; ++i_) { \
      const int k0_ = wid * 32 + i_ * 128; \
      _Pragma("unroll") \
      for (int fm_ = 0; fm_ < 4; ++fm_) \
        fx[i_][fm_] = *(const s16x8*)(Xt_ + (size_t)fm_ * (16 * IDIM) + k0_); \
    } } while (0)

  LOADX(0);

  for (int t = 0; t < L_; ++t) {
    const u16* Hr = Hbuf + (size_t)t * PH;
    u16*       Hw = Hbuf + (size_t)(t + 1) * PH;

    f32x4 acc[4][4];
#pragma unroll
    for (int a = 0; a < 4; ++a)
#pragma unroll
      for (int b = 0; b < 4; ++b)
#pragma unroll
        for (int e = 0; e < 4; ++e) acc[a][b][e] = 0.0f;

    // ---- X phase (independent of other blocks, hides poll) ----
#pragma unroll
    for (int i = 0; i < 4; ++i)
#pragma unroll
      for (int fm = 0; fm < 4; ++fm)
#pragma unroll
        for (int fn = 0; fn < 4; ++fn)
          acc[fm][fn] = __builtin_amdgcn_mfma_f32_16x16x32_bf16(fx[i][fm], breg[i][fn], acc[fm][fn], 0, 0, 0);

    // ---- wait for Hbuf[t] complete (64 sibling blocks) ----
    poll_flags(fgrp, (u32)(t + 1), wid, lane);

    // ---- H phase: plain cached loads (write-once renamed buffers, never stale) ----
    const u16* Hp = Hr + aH;
#pragma unroll
    for (int half = 0; half < 2; ++half) {
      s16x8 fh[4][4];
#pragma unroll
      for (int i = 0; i < 4; ++i) {
        const int kh = wid * 32 + (half * 4 + i) * 128;
#pragma unroll
        for (int fm = 0; fm < 4; ++fm)
          fh[i][fm] = *(const s16x8*)(Hp + (size_t)fm * (16 * H_) + kh);
      }
#pragma unroll
      for (int i = 0; i < 4; ++i)
#pragma unroll
        for (int fm = 0; fm < 4; ++fm)
#pragma unroll
          for (int fn = 0; fn < 4; ++fn)
            acc[fm][fn] = __builtin_amdgcn_mfma_f32_16x16x32_bf16(fh[i][fm], breg[4 + half * 4 + i][fn], acc[fm][fn], 0, 0, 0);
    }

    const int tp1 = (t < L_ - 1) ? (t + 1) : (L_ - 1);
    LOADX(tp1);                               // prefetch next X under epilogue

    // ---- cross-wave K-reduction ----
#pragma unroll
    for (int fm = 0; fm < 4; ++fm)
#pragma unroll
      for (int fn = 0; fn < 4; ++fn)
        *(f32x4*)&S[((wid * 16) + fm * 4 + fn) * 256 + lane * 4] = acc[fm][fn];
    __syncthreads();
    f32x4 red[4];
#pragma unroll
    for (int fn = 0; fn < 4; ++fn) {
      red[fn] = *(const f32x4*)&S[(wid * 4 + fn) * 256 + lane * 4];
#pragma unroll
      for (int w = 1; w < 4; ++w)
        red[fn] += *(const f32x4*)&S[(w * 16 + wid * 4 + fn) * 256 + lane * 4];
    }

    // ---- in-register gate epilogue, write-through H ----
#pragma unroll
    for (int r2 = 0; r2 < 4; ++r2) {
      if (t < lenr[r2]) {
        float gi = red[0][r2] + biasv[0];
        float gf = red[1][r2] + biasv[1];
        float gg = red[2][r2] + biasv[2];
        float go = red[3][r2] + biasv[3];
        float cn = sigf(gf) * cst[r2] + sigf(gi) * tanhf_(gg);
        cst[r2] = cn;
        hst[r2] = sigf(go) * tanhf_(cn);
      }
      st_pair(&Hw[(size_t)(prow + r2) * H_ + j0 + lrow], hst[r2], lane);
    }
    __syncthreads();                          // drain stores (all waves)
    if (tid == 0) set_flag(myflag, (u32)(t + 2));
  }

  // ================= tail =================
  const u16* hfin = Hbuf + (size_t)L_ * PH;
  poll_flags(fgrp, 65u, wid, lane);

  // ---- v = h@Wv^T + bv ----
  {
    f32x4 acc2[4];
#pragma unroll
    for (int a = 0; a < 4; ++a)
#pragma unroll
      for (int e = 0; e < 4; ++e) acc2[a][e] = 0.0f;
    const u16* hp = hfin + aH;
    const float* wv = Win + (size_t)(2 * H_ + j0 + lrow) * H_;
#pragma unroll
    for (int ic = 0; ic < 8; ++ic) {
      const int k0 = wid * 256 + ic * 32;
      s16x8 fbv = pack8(wv + k0 + lgrp * 8);
#pragma unroll
      for (int fm = 0; fm < 4; ++fm) {
        s16x8 fav = *(const s16x8*)(hp + (size_t)fm * (16 * H_) + k0);
        acc2[fm] = __builtin_amdgcn_mfma_f32_16x16x32_bf16(fav, fbv, acc2[fm], 0, 0, 0);
      }
    }
#pragma unroll
    for (int fm = 0; fm < 4; ++fm)
      *(f32x4*)&S[(wid * 4 + fm) * 256 + lane * 4] = acc2[fm];
    __syncthreads();
    f32x4 rv = *(const f32x4*)&S[(wid) * 256 + lane * 4];
#pragma unroll
    for (int w = 1; w < 4; ++w)
      rv += *(const f32x4*)&S[(w * 4 + wid) * 256 + lane * 4];
    float bvj = bin[2 * H_ + j0 + lrow];
#pragma unroll
    for (int r2 = 0; r2 < 4; ++r2)
      st_pair(&vbuf[(size_t)(prow + r2) * H_ + j0 + lrow], rv[r2] + bvj, lane);
  }
  __syncthreads();
  if (tid == 0) set_flag(myflag, 66u);
  poll_flags(fgrp, 66u, wid, lane);

  // ---- attn = v@Wout^T + bout, then per-block max over own 64 rows ----
  {
    f32x4 acc2[4];
#pragma unroll
    for (int a = 0; a < 4; ++a)
#pragma unroll
      for (int e = 0; e < 4; ++e) acc2[a][e] = 0.0f;
    const u16* vp = vbuf + aH;
    const float* wo = Wout + (size_t)(j0 + lrow) * H_;
#pragma unroll
    for (int ic = 0; ic < 8; ++ic) {
      const int k0 = wid * 256 + ic * 32;
      s16x8 fbv = pack8(wo + k0 + lgrp * 8);
#pragma unroll
      for (int fm = 0; fm < 4; ++fm) {
        s16x8 fav = *(const s16x8*)(vp + (size_t)fm * (16 * H_) + k0);
        acc2[fm] = __builtin_amdgcn_mfma_f32_16x16x32_bf16(fav, fbv, acc2[fm], 0, 0, 0);
      }
    }
#pragma unroll
    for (int fm = 0; fm < 4; ++fm)
      *(f32x4*)&S[(wid * 4 + fm) * 256 + lane * 4] = acc2[fm];
    __syncthreads();
    f32x4 rv = *(const f32x4*)&S[(wid) * 256 + lane * 4];
#pragma unroll
    for (int w = 1; w < 4; ++w)
      rv += *(const f32x4*)&S[(w * 4 + wid) * 256 + lane * 4];
    float bo = bout[j0 + lrow];
    float m = fmaxf(fmaxf(rv[0], rv[1]), fmaxf(rv[2], rv[3])) + bo;
    __syncthreads();
    S[(wid * 4 + lgrp) * 16 + lrow] = m;
    __syncthreads();
    if (tid < 16) {
      float mx = S[tid];
#pragma unroll
      for (int s2 = 1; s2 < 16; ++s2) mx = fmaxf(mx, S[s2 * 16 + tid]);
      __hip_atomic_store(&pmax[(size_t)g * H_ + j0 + tid], mx, __ATOMIC_RELAXED, __HIP_MEMORY_SCOPE_AGENT);
    }
  }
  __syncthreads();
  if (tid == 0) set_flag(myflag, 67u);

  if (bid != 0) return;

  // ---- final: max over groups, 1024->2 dot, sigmoid ----
  if (wid == 0) {
    for (int g2 = 0; g2 < 4; ++g2) {
      for (;;) {
        u32 f = __hip_atomic_load(&flags[g2 * 64 + lane], __ATOMIC_RELAXED, __HIP_MEMORY_SCOPE_AGENT);
        if (__all((int)(f >= 67u))) break;
        __builtin_amdgcn_s_sleep(1);
      }
    }
  }
  asm volatile("" ::: "memory");
  __syncthreads();
  {
    int j4 = tid * 4;
    float s0 = 0.f, s1 = 0.f;
#pragma unroll
    for (int e = 0; e < 4; ++e) {
      float pv = pmax[j4 + e];
#pragma unroll
      for (int gg2 = 1; gg2 < 4; ++gg2) pv = fmaxf(pv, pmax[gg2 * H_ + j4 + e]);
      s0 += pv * Wlin[j4 + e];
      s1 += pv * Wlin[H_ + j4 + e];
    }
    S[tid] = s0; S[256 + tid] = s1;
    __syncthreads();
    for (int s2 = 128; s2 > 0; s2 >>= 1) {
      if (tid < s2) { S[tid] += S[tid + s2]; S[256 + tid] += S[256 + tid + s2]; }
      __syncthreads();
    }
    if (tid == 0) {
      out[0] = sigf(S[0] + blin[0]);
      out[1] = sigf(S[256] + blin[1]);
    }
  }
}

extern "C" void kernel_launch(void* const* d_in, const int* in_sizes, int n_in,
                              void* d_out, int out_size, void* d_ws, size_t ws_size,
                              hipStream_t stream) {
  const int*   paths   = (const int*)d_in[0];
  const int*   lengths = (const int*)d_in[1];
  const float* emb     = (const float*)d_in[2];
  const float* Wih     = (const float*)d_in[3];
  const float* Whh     = (const float*)d_in[4];
  const float* bih     = (const float*)d_in[5];
  const float* bhh     = (const float*)d_in[6];
  const float* Win     = (const float*)d_in[7];
  const float* bin     = (const float*)d_in[8];
  const float* Wout    = (const float*)d_in[9];
  const float* bout    = (const float*)d_in[10];
  const float* Wlin    = (const float*)d_in[11];
  const float* blin    = (const float*)d_in[12];
  float* out = (float*)d_out;

  char* ws = (char*)d_ws;
  u32*   flags  = (u32*)  (ws);                  //      1,024 (256 u32; group g at +g*256B)
  float* pmax   = (float*)(ws + 4096);           //     16,384
  u16*   X      = (u16*)  (ws + 32768);          // 16,777,216
  u16*   Hbuf   = (u16*)  (ws + 16810240);       // 65 x 524,288 = 34,078,720
  u16*   vbuf   = (u16*)  (ws + 50888960);       //    524,288   (total ~51.4 MB)

  hipMemsetAsync(flags, 0, 1024, stream);
  tagger_net<<<256, 256, 0, stream>>>(paths, lengths, emb, Wih, Whh, bih, bhh,
                                      Win, bin, Wout, bout, Wlin, blin,
                                      X, Hbuf, vbuf, pmax, flags, out);
}